// Round 26
// baseline (24.377 us; speedup 1.0000x reference)
//
#include <hip/hip_runtime.h>

// Y[b,e,k,j] = sum_i X[b, ind[b,e,k], i] * W[e,i,j]
// X:[B,T,I] f32, ind:[B,E,K] int32, W:[E,I,J] f32 -> Y:[B,E,K,J] f32
#define B_ 8
#define T_ 8192
#define I_ 128
#define E_ 16
#define J_ 128
#define K_ 1024
#define TR 64      // k-rows per tile; 4 tiles per block (512 threads)

typedef unsigned short u16;
typedef unsigned int   u32;
typedef __attribute__((ext_vector_type(8))) short s8v;   // 8 bf16 = 4 VGPRs
typedef __attribute__((ext_vector_type(4))) float f4v;   // MFMA accumulator

__device__ __forceinline__ u16 f2bf(float f) {
    union { float f; u32 u; } v; v.f = f;
    const u32 u = v.u;
    return (u16)((u + 0x7fffu + ((u >> 16) & 1u)) >> 16);  // RNE, branch-free
}

// ---- Single-dispatch, all-resident main (r23/r25 base, best measured):
// inline W convert + per-instruction-coalesced gather + MFMA.
// 4 tiles of 64 rows, double-buffered Xs (64KB, 2 blocks/CU, grid 512).
// ONLY change vs r25: T5 s_setprio(1) around each tile's MFMA cluster —
// the 2 co-resident blocks are phase-shifted (one stages while the other
// computes), so boosting compute-phase waves shortens the accumulate
// critical path each barrier waits on.
__global__ __launch_bounds__(512, 4)
void gather_mfma(const float* __restrict__ X, const int* __restrict__ ind,
                 const float* __restrict__ W, float* __restrict__ Y) {
    __shared__ u16 WsT[I_ * J_];
    __shared__ u16 XsA[TR * I_];
    __shared__ u16 XsB[TR * I_];

    const int t    = threadIdx.x;
    const int wave = t >> 6;
    const int lane = t & 63;

    // XCD b-affinity swizzle: grid=512, 8 XCDs. XCD x gets bid 64x..64x+63
    // -> b = bid>>6 = x (X[b] 4MB L2-resident per XCD).
    const int orig = blockIdx.x;
    const int bid  = (orig & 7) * 64 + (orig >> 3);
    const int kh = bid & 3;              // K/256 = 4 quad-tiles
    const int be = bid >> 2;
    const int e  = be & (E_ - 1);
    const int b  = be >> 4;
    const int k0 = kh * (4 * TR);        // 256-row range

    // Gather lane geometry + all 16 token indices up-front.
    const int ch   = lane & 31;          // f4 chunk within a row (0..31)
    const int rsub = lane >> 5;          // 0/1
    int idx[4][4];
#pragma unroll
    for (int tt = 0; tt < 4; ++tt)
#pragma unroll
        for (int u = 0; u < 4; ++u) {
            const int rw = wave * 2 + rsub + 16 * u;    // 0..63, distinct
            idx[tt][u] = ind[(size_t)be * K_ + k0 + tt * TR + rw];
        }

    // ---- Stage WsT inline (r20 conflict-free form) ----
    {
        const float* We = W + (size_t)e * (I_ * J_);
        const int io = t & 15;           // i-octet 0..15
        const int j0 = (t >> 4) * 4;     // j group 0..124
        float4 w4[8];
#pragma unroll
        for (int u = 0; u < 8; ++u)
            w4[u] = *reinterpret_cast<const float4*>(We + (size_t)(io * 8 + u) * J_ + j0);
#pragma unroll
        for (int qq = 0; qq < 4; ++qq) {
            const int j = j0 + qq;
            s8v o;
#pragma unroll
            for (int u = 0; u < 8; ++u) {
                const float* wf = reinterpret_cast<const float*>(&w4[u]);
                o[u] = (short)f2bf(wf[qq]);
            }
            *reinterpret_cast<s8v*>((char*)WsT + ((j * 256 + io * 16) ^ ((j & 7) << 4))) = o;
        }
    }

    // X staging: per-instruction-coalesced loads (2 full rows / wave-instr),
    // uint2 swizzled LDS writes (r22 pattern, 4 rows/tile/thread).
    float4 v[4];
    auto load_rows = [&](const int (&ii)[4]) {
#pragma unroll
        for (int u = 0; u < 4; ++u)
            v[u] = reinterpret_cast<const float4*>(X + ((size_t)b * T_ + ii[u]) * I_)[ch];
    };
    auto pack_write = [&](u16* Xs) {
#pragma unroll
        for (int u = 0; u < 4; ++u) {
            const int rw = wave * 2 + rsub + 16 * u;
            const float4 a = v[u];
            uint2 o;
            o.x = ((u32)f2bf(a.y) << 16) | f2bf(a.x);
            o.y = ((u32)f2bf(a.w) << 16) | f2bf(a.z);
            *reinterpret_cast<uint2*>((char*)Xs + rw * 256 + ((ch * 8) ^ ((rw & 7) << 4))) = o;
        }
    };

    // ---- Compute decomposition: wave = (rq 0..3, jh); 16 rows x 64 cols ----
    const int rq  = wave >> 1;
    const int jh  = wave & 1;
    const int g   = lane >> 4;
    const int l15 = lane & 15;
    const int sx  = (lane & 7) << 4;
    const char* wb = (const char*)WsT + (size_t)(jh * 64 + l15) * 256;

    auto compute_store = [&](const u16* Xs, int kbase) {
        const char* xb = (const char*)Xs + (size_t)(rq * 16 + l15) * 256;
        s8v af[4];
#pragma unroll
        for (int s = 0; s < 4; ++s) {
            const int off = (s * 64 + g * 16) ^ sx;
            af[s] = *reinterpret_cast<const s8v*>(xb + off);
        }
        float* Yb = Y + ((size_t)be * K_ + kbase) * J_;
        __builtin_amdgcn_s_setprio(1);   // T5: favor compute-phase waves
#pragma unroll
        for (int n = 0; n < 4; ++n) {
            f4v acc;
#pragma unroll
            for (int rr = 0; rr < 4; ++rr) acc[rr] = 0.f;
#pragma unroll
            for (int s = 0; s < 4; ++s) {
                const int off = (s * 64 + g * 16) ^ sx;
                const s8v bf = *reinterpret_cast<const s8v*>(wb + n * 16 * 256 + off);
                acc = __builtin_amdgcn_mfma_f32_16x16x32_bf16(af[s], bf, acc, 0, 0, 0);
            }
            __builtin_amdgcn_s_setprio(0);
            const int col = jh * 64 + n * 16 + l15;
            const int row0 = rq * 16 + g * 4;
#pragma unroll
            for (int rr = 0; rr < 4; ++rr)
                Yb[(size_t)(row0 + rr) * J_ + col] = acc[rr];
            if (n < 3) __builtin_amdgcn_s_setprio(1);
        }
    };

    // ---- Pipeline: 1 barrier per tile transition ----
    load_rows(idx[0]); pack_write(XsA);
    __syncthreads();                          // W + tile0 visible

    load_rows(idx[1]);
    compute_store(XsA, k0);
    pack_write(XsB);
    __syncthreads();

    load_rows(idx[2]);
    compute_store(XsB, k0 + TR);
    pack_write(XsA);                          // tile0 readers drained 2 bars ago
    __syncthreads();

    load_rows(idx[3]);
    compute_store(XsA, k0 + 2 * TR);
    pack_write(XsB);
    __syncthreads();

    compute_store(XsB, k0 + 3 * TR);
}

extern "C" void kernel_launch(void* const* d_in, const int* in_sizes, int n_in,
                              void* d_out, int out_size, void* d_ws, size_t ws_size,
                              hipStream_t stream) {
    (void)in_sizes; (void)n_in; (void)out_size; (void)d_ws; (void)ws_size;
    const float* X   = (const float*)d_in[0];
    const int*   ind = (const int*)d_in[1];
    const float* W   = (const float*)d_in[2];
    float*       Y   = (float*)d_out;

    const int grid = B_ * E_ * (K_ / (4 * TR));   // 512, all-resident
    hipLaunchKernelGGL(gather_mfma, dim3(grid), dim3(512), 0, stream,
                       X, ind, W, Y);
}

// Round 27
// 24.094 us; speedup vs baseline: 1.0117x; 1.0117x over previous
//
#include <hip/hip_runtime.h>

// Y[b,e,k,j] = sum_i X[b, ind[b,e,k], i] * W[e,i,j]
// X:[B,T,I] f32, ind:[B,E,K] int32, W:[E,I,J] f32 -> Y:[B,E,K,J] f32
#define B_ 8
#define T_ 8192
#define I_ 128
#define E_ 16
#define J_ 128
#define K_ 1024
#define TR 64      // k-rows per tile; 4 tiles per block (512 threads)

typedef unsigned short u16;
typedef unsigned int   u32;
typedef __attribute__((ext_vector_type(8))) short s8v;   // 8 bf16 = 4 VGPRs
typedef __attribute__((ext_vector_type(4))) float f4v;   // MFMA accumulator

__device__ __forceinline__ u16 f2bf(float f) {
    union { float f; u32 u; } v; v.f = f;
    const u32 u = v.u;
    return (u16)((u + 0x7fffu + ((u >> 16) & 1u)) >> 16);  // RNE, branch-free
}

// ---- Single-dispatch, all-resident main (r25 base, best measured):
// inline W convert + per-instruction-coalesced gather + MFMA.
// ONLY change vs r25: TRIPLE-buffered Xs (WsT 32K + 3x16K = 80KB ->
// 2 blocks/CU = exactly 160KB/CU, residency unchanged) with X loads
// issued TWO tiles ahead (vA/vB static register sets). Load->use distance
// grows from ~1 compute phase to a full tile + barrier, hiding L2 latency
// and decoupling the pack_write vmcnt wait from the same-tile store burst.
__global__ __launch_bounds__(512, 4)
void gather_mfma(const float* __restrict__ X, const int* __restrict__ ind,
                 const float* __restrict__ W, float* __restrict__ Y) {
    __shared__ u16 WsT[I_ * J_];
    __shared__ u16 Xs0[TR * I_];
    __shared__ u16 Xs1[TR * I_];
    __shared__ u16 Xs2[TR * I_];

    const int t    = threadIdx.x;
    const int wave = t >> 6;
    const int lane = t & 63;

    // XCD b-affinity swizzle: grid=512, 8 XCDs. XCD x gets bid 64x..64x+63
    // -> b = bid>>6 = x (X[b] 4MB L2-resident per XCD).
    const int orig = blockIdx.x;
    const int bid  = (orig & 7) * 64 + (orig >> 3);
    const int kh = bid & 3;              // K/256 = 4 quad-tiles
    const int be = bid >> 2;
    const int e  = be & (E_ - 1);
    const int b  = be >> 4;
    const int k0 = kh * (4 * TR);        // 256-row range

    // Gather lane geometry + all 16 token indices up-front.
    const int ch   = lane & 31;          // f4 chunk within a row (0..31)
    const int rsub = lane >> 5;          // 0/1
    int idx[4][4];
#pragma unroll
    for (int tt = 0; tt < 4; ++tt)
#pragma unroll
        for (int u = 0; u < 4; ++u) {
            const int rw = wave * 2 + rsub + 16 * u;    // 0..63, distinct
            idx[tt][u] = ind[(size_t)be * K_ + k0 + tt * TR + rw];
        }

    // ---- Stage WsT inline (r20 conflict-free form) ----
    {
        const float* We = W + (size_t)e * (I_ * J_);
        const int io = t & 15;           // i-octet 0..15
        const int j0 = (t >> 4) * 4;     // j group 0..124
        float4 w4[8];
#pragma unroll
        for (int u = 0; u < 8; ++u)
            w4[u] = *reinterpret_cast<const float4*>(We + (size_t)(io * 8 + u) * J_ + j0);
#pragma unroll
        for (int qq = 0; qq < 4; ++qq) {
            const int j = j0 + qq;
            s8v o;
#pragma unroll
            for (int u = 0; u < 8; ++u) {
                const float* wf = reinterpret_cast<const float*>(&w4[u]);
                o[u] = (short)f2bf(wf[qq]);
            }
            *reinterpret_cast<s8v*>((char*)WsT + ((j * 256 + io * 16) ^ ((j & 7) << 4))) = o;
        }
    }

    // X staging: per-instruction-coalesced loads (2 full rows / wave-instr),
    // uint2 swizzled LDS writes. Two static register sets vA, vB (rule #20).
    float4 vA[4], vB[4];
#define LOAD_ROWS(vv, tt)                                                      \
    {                                                                          \
        _Pragma("unroll")                                                      \
        for (int u_ = 0; u_ < 4; ++u_)                                         \
            vv[u_] = reinterpret_cast<const float4*>(                          \
                X + ((size_t)b * T_ + idx[tt][u_]) * I_)[ch];                  \
    }
#define PACK_WRITE(Xs, vv)                                                     \
    {                                                                          \
        _Pragma("unroll")                                                      \
        for (int u_ = 0; u_ < 4; ++u_) {                                       \
            const int rw_ = wave * 2 + rsub + 16 * u_;                         \
            const float4 a_ = vv[u_];                                          \
            uint2 o_;                                                          \
            o_.x = ((u32)f2bf(a_.y) << 16) | f2bf(a_.x);                       \
            o_.y = ((u32)f2bf(a_.w) << 16) | f2bf(a_.z);                       \
            *reinterpret_cast<uint2*>((char*)Xs + rw_ * 256 +                  \
                                      ((ch * 8) ^ ((rw_ & 7) << 4))) = o_;     \
        }                                                                      \
    }

    // ---- Compute decomposition: wave = (rq 0..3, jh); 16 rows x 64 cols ----
    const int rq  = wave >> 1;
    const int jh  = wave & 1;
    const int g   = lane >> 4;
    const int l15 = lane & 15;
    const int sx  = (lane & 7) << 4;
    const char* wb = (const char*)WsT + (size_t)(jh * 64 + l15) * 256;

    auto compute_store = [&](const u16* Xs, int kbase) {
        const char* xb = (const char*)Xs + (size_t)(rq * 16 + l15) * 256;
        s8v af[4];
#pragma unroll
        for (int s = 0; s < 4; ++s) {
            const int off = (s * 64 + g * 16) ^ sx;
            af[s] = *reinterpret_cast<const s8v*>(xb + off);
        }
        float* Yb = Y + ((size_t)be * K_ + kbase) * J_;
#pragma unroll
        for (int n = 0; n < 4; ++n) {
            f4v acc;
#pragma unroll
            for (int rr = 0; rr < 4; ++rr) acc[rr] = 0.f;
#pragma unroll
            for (int s = 0; s < 4; ++s) {
                const int off = (s * 64 + g * 16) ^ sx;
                const s8v bf = *reinterpret_cast<const s8v*>(wb + n * 16 * 256 + off);
                acc = __builtin_amdgcn_mfma_f32_16x16x32_bf16(af[s], bf, acc, 0, 0, 0);
            }
            const int col = jh * 64 + n * 16 + l15;
            const int row0 = rq * 16 + g * 4;
#pragma unroll
            for (int rr = 0; rr < 4; ++rr)
                Yb[(size_t)(row0 + rr) * J_ + col] = acc[rr];
        }
    };

    // ---- Pipeline, prefetch depth 2, 1 barrier per tile transition ----
    LOAD_ROWS(vA, 0); PACK_WRITE(Xs0, vA);    // tile0 staged directly
    LOAD_ROWS(vB, 1);                         // prefetch tile1
    __syncthreads();                          // W + tile0 visible

    LOAD_ROWS(vA, 2);                         // prefetch tile2 (2 ahead)
    compute_store(Xs0, k0);
    PACK_WRITE(Xs1, vB);                      // vB loaded a full tile ago
    __syncthreads();

    LOAD_ROWS(vB, 3);                         // prefetch tile3 (2 ahead)
    compute_store(Xs1, k0 + TR);
    PACK_WRITE(Xs2, vA);
    __syncthreads();

    compute_store(Xs2, k0 + 2 * TR);
    PACK_WRITE(Xs0, vB);                      // Xs0 last read 2 bars ago
    __syncthreads();

    compute_store(Xs0, k0 + 3 * TR);
#undef LOAD_ROWS
#undef PACK_WRITE
}

extern "C" void kernel_launch(void* const* d_in, const int* in_sizes, int n_in,
                              void* d_out, int out_size, void* d_ws, size_t ws_size,
                              hipStream_t stream) {
    (void)in_sizes; (void)n_in; (void)out_size; (void)d_ws; (void)ws_size;
    const float* X   = (const float*)d_in[0];
    const int*   ind = (const int*)d_in[1];
    const float* W   = (const float*)d_in[2];
    float*       Y   = (float*)d_out;

    const int grid = B_ * E_ * (K_ / (4 * TR));   // 512, all-resident
    hipLaunchKernelGGL(gather_mfma, dim3(grid), dim3(512), 0, stream,
                       X, ind, W, Y);
}